// Round 7
// baseline (111.315 us; speedup 1.0000x reference)
//
#include <hip/hip_runtime.h>
#include <stdint.h>

#define N      8192
#define KDIM   256
#define BM     128
#define TILES  (N / BM)                    // 64
#define NPAIRS (TILES * (TILES + 1) / 2)   // 2080
#define MARGIN 0.5f
#define PLANE_Q ((size_t)N * 64)           // one quarter-K plane of Xq (512 KB)

typedef float     f32x4 __attribute__((ext_vector_type(4)));
typedef long long i64x2 __attribute__((ext_vector_type(2)));

// async global->LDS, 16 B/lane; LDS dest = wave-uniform base + lane*16
__device__ __forceinline__ void async_copy16(const void* g, void* l) {
    __builtin_amdgcn_global_load_lds(
        (__attribute__((address_space(1))) void*)(g),
        (__attribute__((address_space(3))) void*)(l),
        16, 0, 0);
}

#if !__has_builtin(__builtin_amdgcn_cvt_pk_fp8_f32)
// manual fp32 -> e4m3fn RNE fallback
__device__ __forceinline__ uint32_t f2e4m3(float f) {
    uint32_t u = __float_as_uint(f);
    uint32_t s = (u >> 24) & 0x80u;
    uint32_t au = u & 0x7fffffffu;
    if (au == 0) return s;
    int32_t  exp = (int32_t)(au >> 23) - 127;
    uint32_t man = (au & 0x7fffffu) | 0x800000u;
    uint32_t code;
    if (exp >= -6) {
        code = (uint32_t)((exp + 7) << 3) | ((man >> 20) & 7u);
        uint32_t rem = man & 0xFFFFFu;
        if (rem > 0x80000u || (rem == 0x80000u && (code & 1u))) code++;
    } else {
        int shift = 14 - exp;
        if (shift > 24) return s;
        code = man >> shift;
        uint32_t rem = man & ((1u << shift) - 1u);
        uint32_t h = 1u << (shift - 1);
        if (rem > h || (rem == h && (code & 1u))) code++;
    }
    return s | code;
}
__device__ __forceinline__ uint32_t pack_fp8x4(float4 v) {
    return f2e4m3(v.x) | (f2e4m3(v.y) << 8) | (f2e4m3(v.z) << 16) |
           (f2e4m3(v.w) << 24);
}
#else
__device__ __forceinline__ uint32_t pack_fp8x4(float4 v) {
    int pk = __builtin_amdgcn_cvt_pk_fp8_f32(v.x, v.y, 0, false);
    pk = __builtin_amdgcn_cvt_pk_fp8_f32(v.z, v.w, pk, true);
    return (uint32_t)pk;
}
#endif

// ---------------------------------------------------------------------------
// Prepass: fp32 -> fp8 e4m3 into FOUR quarter-K planes (validated r6 layout).
// Within a quarter-row (64 B): byte = chunk*16 + kstep*8 + b. One 16 B
// granule per (row, chunk) feeds both k-steps of one lane's MFMA operand
// (i64x2 .x/.y); LDS granule index == frow -> conflict-free ds_read_b128.
// Packs per-row metadata {sq_bits, tgt} (8 B). Also zeroes the ticket.
// ---------------------------------------------------------------------------
__global__ __launch_bounds__(256) void prep_kernel(
        const float* __restrict__ X, const int* __restrict__ tgt,
        uint8_t* __restrict__ Xq, uint2* __restrict__ metaG,
        uint32_t* __restrict__ ticket) {
    if (blockIdx.x == 0 && threadIdx.x == 0) *ticket = 0;

    int row  = blockIdx.x * 4 + (threadIdx.x >> 6);
    int lane = threadIdx.x & 63;

    float4 v = *((const float4*)(X + (size_t)row * KDIM) + lane);
    float ss = v.x * v.x + v.y * v.y + v.z * v.z + v.w * v.w;
    uint32_t pk = pack_fp8x4(v);

    int k0 = lane * 4;            // global k of first element
    int u  = k0 >> 6;             // quarter-K plane
    int rem = k0 & 63;
    int ks  = rem >> 5;           // k-step within unit (0/1)
    int ch  = (rem >> 3) & 3;     // 8-elem chunk (fquad) within k-step
    size_t off = (size_t)u * PLANE_Q + (size_t)row * 64
               + ch * 16 + ks * 8 + (k0 & 7);
    *(uint32_t*)(Xq + off) = pk;

    #pragma unroll
    for (int o = 32; o > 0; o >>= 1) ss += __shfl_down(ss, o, 64);
    if (lane == 0)
        metaG[row] = make_uint2(__float_as_uint(ss), (uint32_t)tgt[row]);
}

// ---------------------------------------------------------------------------
// Compute one K=64 unit: 4 a-frags + 4 b-frags (ds_read_b128, conflict-free),
// 32 MFMAs wrapped in s_setprio (T5).
// ---------------------------------------------------------------------------
__device__ __forceinline__ void compute_unit(
        const uint8_t* Au, const uint8_t* Bu, int wm4, int wn4, int fragOff,
        f32x4 (&acc)[4][4]) {
    i64x2 a2[4], b2[4];
    #pragma unroll
    for (int im = 0; im < 4; ++im)
        a2[im] = *(const i64x2*)(Au + (size_t)(wm4 + im) * 1024 + fragOff);
    #pragma unroll
    for (int in = 0; in < 4; ++in)
        b2[in] = *(const i64x2*)(Bu + (size_t)(wn4 + in) * 1024 + fragOff);
    __builtin_amdgcn_s_setprio(1);
    #pragma unroll
    for (int im = 0; im < 4; ++im)
        #pragma unroll
        for (int in = 0; in < 4; ++in)
            acc[im][in] = __builtin_amdgcn_mfma_f32_16x16x32_fp8_fp8(
                a2[im].x, b2[in].x, acc[im][in], 0, 0, 0);
    #pragma unroll
    for (int im = 0; im < 4; ++im)
        #pragma unroll
        for (int in = 0; in < 4; ++in)
            acc[im][in] = __builtin_amdgcn_mfma_f32_16x16x32_fp8_fp8(
                a2[im].y, b2[in].y, acc[im][in], 0, 0, 0);
    __builtin_amdgcn_s_setprio(0);
}

// issue one unit's staging: per wave rowblks {2w,2w+1} of A and B (4 instr)
__device__ __forceinline__ void stage_unit(
        const uint8_t* gA, const uint8_t* gB,
        uint8_t* lA, uint8_t* lB, int wave) {
    size_t o0 = (size_t)(2 * wave) * 1024, o1 = o0 + 1024;
    async_copy16(gA + o0, lA + o0);
    async_copy16(gA + o1, lA + o1);
    async_copy16(gB + o0, lB + o0);
    async_copy16(gB + o1, lB + o1);
}

#define WAITV(n) asm volatile("s_waitcnt vmcnt(" #n ")" ::: "memory")
#define SBAR()   do { __builtin_amdgcn_sched_barrier(0);                 \
                      __builtin_amdgcn_s_barrier();                      \
                      __builtin_amdgcn_sched_barrier(0); } while (0)

// ---------------------------------------------------------------------------
// Main: triangular grid of 128x128 Gram tiles, fp8 MFMA. K split into 4
// units of 64, double-buffered 8+8 KB -> 34 KB LDS -> 4 blocks/CU, with the
// r6 non-draining counted-vmcnt pipeline. Fused loss epilogue (metadata
// hoisted to registers) + fused last-block deterministic final reduce.
// ---------------------------------------------------------------------------
__global__ __launch_bounds__(256, 4) void loss_kernel(
        const uint8_t* __restrict__ Xq, const uint2* __restrict__ metaG,
        float* __restrict__ partials, uint32_t* __restrict__ ticket,
        float* __restrict__ out, float scale) {
    // ---- triangular decode: p -> (bi, bj), bi <= bj ----
    const int p = blockIdx.x;
    float tf = 2.0f * TILES + 1.0f;
    int bi = (int)((tf - sqrtf(tf * tf - 8.0f * (float)p)) * 0.5f);
    if (bi < 0) bi = 0;
    while (bi > 0 && (bi * TILES - bi * (bi - 1) / 2) > p) --bi;
    while (((bi + 1) * TILES - (bi + 1) * bi / 2) <= p) ++bi;
    const int bj = bi + (p - (bi * TILES - bi * (bi - 1) / 2));

    __shared__ __align__(16) uint8_t As[2][8192];   // 16 KB  (K=64 units)
    __shared__ __align__(16) uint8_t Bs[2][8192];   // 16 KB
    __shared__ __align__(16) uint2   metaA[BM], metaB[BM];  // {sq,tgt} 2 KB
    __shared__ float wsum[4];
    __shared__ int   winner;

    const int tid  = threadIdx.x;
    const int wave = tid >> 6;
    const int lane = tid & 63;

    const int frow  = lane & 15;
    const int fquad = lane >> 4;
    const int wm4 = (wave >> 1) * 4;       // A rowblk base (rows wm=wm4*16)
    const int wn4 = (wave & 1) * 4;        // B rowblk base
    const int fragOff = fquad * 256 + frow * 16;

    // per-lane global source offset: granule (chunk=lane>>4) of row (lane&15)
    const size_t srcLane = (size_t)(lane & 15) * 64 + (size_t)(lane >> 4) * 16;
    const uint8_t* gA = Xq + (size_t)bi * BM * 64 + srcLane;
    const uint8_t* gB = Xq + (size_t)bj * BM * 64 + srcLane;

    // ---- issue: meta (2) + unit0 (4) + unit1 (4) = 10 in flight ----
    async_copy16((const uint8_t*)(metaG + bi * BM) + (size_t)lane * 16, metaA);
    async_copy16((const uint8_t*)(metaG + bj * BM) + (size_t)lane * 16, metaB);
    stage_unit(gA,            gB,            As[0], Bs[0], wave);
    stage_unit(gA + PLANE_Q,  gB + PLANE_Q,  As[1], Bs[1], wave);

    f32x4 acc[4][4];
    #pragma unroll
    for (int im = 0; im < 4; ++im)
        #pragma unroll
        for (int in = 0; in < 4; ++in)
            acc[im][in] = (f32x4){0.f, 0.f, 0.f, 0.f};

    WAITV(4); SBAR();                      // meta + unit0 ready; u1 in flight
    compute_unit(As[0], Bs[0], wm4, wn4, fragOff, acc);
    SBAR();                                // buf0 reads retired everywhere
    stage_unit(gA + 2 * PLANE_Q, gB + 2 * PLANE_Q, As[0], Bs[0], wave);

    WAITV(4); SBAR();                      // unit1 ready; u2 in flight
    compute_unit(As[1], Bs[1], wm4, wn4, fragOff, acc);
    SBAR();                                // buf1 reads retired everywhere
    stage_unit(gA + 3 * PLANE_Q, gB + 3 * PLANE_Q, As[1], Bs[1], wave);

    WAITV(4); SBAR();                      // unit2 ready; u3 in flight
    compute_unit(As[0], Bs[0], wm4, wn4, fragOff, acc);

    WAITV(0); SBAR();                      // unit3 ready (landed during u2)
    compute_unit(As[1], Bs[1], wm4, wn4, fragOff, acc);

    // ---- epilogue: C/D map col=lane&15, row=(lane>>4)*4+reg ----
    const int wm = wm4 * 16, wn = wn4 * 16;
    // hoist column metadata (depends only on in,frow): 4 regs
    uint2 mb[4];
    #pragma unroll
    for (int in = 0; in < 4; ++in) mb[in] = metaB[wn + in * 16 + frow];

    float lsum = 0.0f;
    if (bi != bj) {
        #pragma unroll
        for (int im = 0; im < 4; ++im) {
            #pragma unroll
            for (int r = 0; r < 4; ++r) {
                uint2 ma = metaA[wm + im * 16 + fquad * 4 + r];
                #pragma unroll
                for (int in = 0; in < 4; ++in) {
                    float d = fmaf(-2.0f, acc[im][in][r],
                                   __uint_as_float(ma.x) + __uint_as_float(mb[in].x));
                    lsum += (ma.y == mb[in].y) ? d : fmaxf(MARGIN - d, 0.0f);
                }
            }
        }
        lsum *= 2.0f;   // (i,j) and (j,i)
    } else {
        #pragma unroll
        for (int im = 0; im < 4; ++im) {
            #pragma unroll
            for (int r = 0; r < 4; ++r) {
                int rl = wm + im * 16 + fquad * 4 + r;
                uint2 ma = metaA[rl];
                #pragma unroll
                for (int in = 0; in < 4; ++in) {
                    int cl = wn + in * 16 + frow;
                    float d = fmaf(-2.0f, acc[im][in][r],
                                   __uint_as_float(ma.x) + __uint_as_float(mb[in].x));
                    float c = (ma.y == mb[in].y) ? d : fmaxf(MARGIN - d, 0.0f);
                    float w = (rl < cl) ? 2.0f : ((rl == cl) ? 1.0f : 0.0f);
                    lsum += w * c;
                }
            }
        }
    }

    #pragma unroll
    for (int o = 32; o > 0; o >>= 1) lsum += __shfl_down(lsum, o, 64);
    if (lane == 0) wsum[wave] = lsum;
    __syncthreads();

    // ---- last-block fused deterministic reduce ----
    if (tid == 0) {
        partials[p] = wsum[0] + wsum[1] + wsum[2] + wsum[3];
        __threadfence();                       // make store device-visible
        uint32_t t = atomicAdd(ticket, 1u);    // device-scope
        winner = (t == NPAIRS - 1) ? 1 : 0;
    }
    __syncthreads();
    if (winner) {
        __threadfence();
        float s = 0.0f;
        for (int i = tid; i < NPAIRS; i += 256)
            s += __hip_atomic_load(&partials[i], __ATOMIC_RELAXED,
                                   __HIP_MEMORY_SCOPE_AGENT);
        #pragma unroll
        for (int o = 32; o > 0; o >>= 1) s += __shfl_down(s, o, 64);
        if (lane == 0) wsum[wave] = s;
        __syncthreads();
        if (tid == 0)
            out[0] = (wsum[0] + wsum[1] + wsum[2] + wsum[3]) * scale;
    }
}

extern "C" void kernel_launch(void* const* d_in, const int* in_sizes, int n_in,
                              void* d_out, int out_size, void* d_ws, size_t ws_size,
                              hipStream_t stream) {
    (void)in_sizes; (void)n_in; (void)out_size; (void)ws_size;
    const float* X   = (const float*)d_in[0];
    const int*   tgt = (const int*)d_in[1];

    uint8_t*  Xq       = (uint8_t*)d_ws;                             // 2 MB (4 planes)
    uint2*    metaG    = (uint2*)((char*)d_ws + 4 * PLANE_Q);        // 64 KB
    float*    partials = (float*)((char*)metaG + (size_t)N * 8);     // NPAIRS
    uint32_t* ticket   = (uint32_t*)(partials + NPAIRS);

    const float scale = (float)(1.0 / ((double)N * ((double)N - 1.0) * 2.0));

    prep_kernel<<<N / 4, 256, 0, stream>>>(X, tgt, Xq, metaG, ticket);
    loss_kernel<<<NPAIRS, 256, 0, stream>>>(Xq, metaG, partials, ticket,
                                            (float*)d_out, scale);
}

// Round 8
// 86.110 us; speedup vs baseline: 1.2927x; 1.2927x over previous
//
#include <hip/hip_runtime.h>
#include <stdint.h>

#define N      8192
#define KDIM   256
#define BM     128
#define TILES  (N / BM)                    // 64
#define NPAIRS (TILES * (TILES + 1) / 2)   // 2080
#define NBLK   (NPAIRS / 2)                // 1040 loss blocks, 2 pairs each
#define MARGIN 0.5f
#define PLANE_Q ((size_t)N * 64)           // one quarter-K plane of Xq (512 KB)

typedef float     f32x4 __attribute__((ext_vector_type(4)));
typedef long long i64x2 __attribute__((ext_vector_type(2)));

// async global->LDS, 16 B/lane; LDS dest = wave-uniform base + lane*16
__device__ __forceinline__ void async_copy16(const void* g, void* l) {
    __builtin_amdgcn_global_load_lds(
        (__attribute__((address_space(1))) void*)(g),
        (__attribute__((address_space(3))) void*)(l),
        16, 0, 0);
}

#if !__has_builtin(__builtin_amdgcn_cvt_pk_fp8_f32)
// manual fp32 -> e4m3fn RNE fallback
__device__ __forceinline__ uint32_t f2e4m3(float f) {
    uint32_t u = __float_as_uint(f);
    uint32_t s = (u >> 24) & 0x80u;
    uint32_t au = u & 0x7fffffffu;
    if (au == 0) return s;
    int32_t  exp = (int32_t)(au >> 23) - 127;
    uint32_t man = (au & 0x7fffffu) | 0x800000u;
    uint32_t code;
    if (exp >= -6) {
        code = (uint32_t)((exp + 7) << 3) | ((man >> 20) & 7u);
        uint32_t rem = man & 0xFFFFFu;
        if (rem > 0x80000u || (rem == 0x80000u && (code & 1u))) code++;
    } else {
        int shift = 14 - exp;
        if (shift > 24) return s;
        code = man >> shift;
        uint32_t rem = man & ((1u << shift) - 1u);
        uint32_t h = 1u << (shift - 1);
        if (rem > h || (rem == h && (code & 1u))) code++;
    }
    return s | code;
}
__device__ __forceinline__ uint32_t pack_fp8x4(float4 v) {
    return f2e4m3(v.x) | (f2e4m3(v.y) << 8) | (f2e4m3(v.z) << 16) |
           (f2e4m3(v.w) << 24);
}
#else
__device__ __forceinline__ uint32_t pack_fp8x4(float4 v) {
    int pk = __builtin_amdgcn_cvt_pk_fp8_f32(v.x, v.y, 0, false);
    pk = __builtin_amdgcn_cvt_pk_fp8_f32(v.z, v.w, pk, true);
    return (uint32_t)pk;
}
#endif

// ---------------------------------------------------------------------------
// Prepass: fp32 -> fp8 e4m3 into FOUR quarter-K planes (validated r6 layout).
// Within a quarter-row (64 B): byte = chunk*16 + kstep*8 + b. One 16 B
// granule per (row, chunk) feeds both k-steps of one lane's MFMA operand
// (i64x2 .x/.y); LDS granule index == frow -> conflict-free ds_read_b128.
// Packs per-row metadata {sq_bits, tgt} (8 B).
// ---------------------------------------------------------------------------
__global__ __launch_bounds__(256) void prep_kernel(
        const float* __restrict__ X, const int* __restrict__ tgt,
        uint8_t* __restrict__ Xq, uint2* __restrict__ metaG) {
    int row  = blockIdx.x * 4 + (threadIdx.x >> 6);
    int lane = threadIdx.x & 63;

    float4 v = *((const float4*)(X + (size_t)row * KDIM) + lane);
    float ss = v.x * v.x + v.y * v.y + v.z * v.z + v.w * v.w;
    uint32_t pk = pack_fp8x4(v);

    int k0 = lane * 4;            // global k of first element
    int u  = k0 >> 6;             // quarter-K plane
    int rem = k0 & 63;
    int ks  = rem >> 5;           // k-step within unit (0/1)
    int ch  = (rem >> 3) & 3;     // 8-elem chunk (fquad) within k-step
    size_t off = (size_t)u * PLANE_Q + (size_t)row * 64
               + ch * 16 + ks * 8 + (k0 & 7);
    *(uint32_t*)(Xq + off) = pk;

    #pragma unroll
    for (int o = 32; o > 0; o >>= 1) ss += __shfl_down(ss, o, 64);
    if (lane == 0)
        metaG[row] = make_uint2(__float_as_uint(ss), (uint32_t)tgt[row]);
}

// ---------------------------------------------------------------------------
// Compute one K=64 unit: 4 a-frags + 4 b-frags (ds_read_b128, conflict-free),
// 32 MFMAs. (No setprio: T5 measured null/negative on lockstep schedules.)
// ---------------------------------------------------------------------------
__device__ __forceinline__ void compute_unit(
        const uint8_t* Au, const uint8_t* Bu, int wm4, int wn4, int fragOff,
        f32x4 (&acc)[4][4]) {
    i64x2 a2[4], b2[4];
    #pragma unroll
    for (int im = 0; im < 4; ++im)
        a2[im] = *(const i64x2*)(Au + (size_t)(wm4 + im) * 1024 + fragOff);
    #pragma unroll
    for (int in = 0; in < 4; ++in)
        b2[in] = *(const i64x2*)(Bu + (size_t)(wn4 + in) * 1024 + fragOff);
    #pragma unroll
    for (int im = 0; im < 4; ++im)
        #pragma unroll
        for (int in = 0; in < 4; ++in)
            acc[im][in] = __builtin_amdgcn_mfma_f32_16x16x32_fp8_fp8(
                a2[im].x, b2[in].x, acc[im][in], 0, 0, 0);
    #pragma unroll
    for (int im = 0; im < 4; ++im)
        #pragma unroll
        for (int in = 0; in < 4; ++in)
            acc[im][in] = __builtin_amdgcn_mfma_f32_16x16x32_fp8_fp8(
                a2[im].y, b2[in].y, acc[im][in], 0, 0, 0);
}

// issue one unit's staging: per wave rowblks {2w,2w+1} of A and B (4 instr)
__device__ __forceinline__ void stage_unit(
        const uint8_t* gA, const uint8_t* gB,
        uint8_t* lA, uint8_t* lB, int wave) {
    size_t o0 = (size_t)(2 * wave) * 1024, o1 = o0 + 1024;
    async_copy16(gA + o0, lA + o0);
    async_copy16(gA + o1, lA + o1);
    async_copy16(gB + o0, lB + o0);
    async_copy16(gB + o1, lB + o1);
}

// fused contrastive-loss epilogue for one pair; C/D map col=lane&15,
// row=(lane>>4)*4+reg (validated). Returns this thread's contribution
// (off-diagonal pairs pre-scaled by 2).
__device__ __forceinline__ float epilogue(
        const f32x4 (&acc)[4][4], const uint2* mAs, const uint2* mBs,
        int bi, int bj, int wm, int wn, int frow, int fquad) {
    uint2 mb[4];
    #pragma unroll
    for (int in = 0; in < 4; ++in) mb[in] = mBs[wn + in * 16 + frow];

    float lsum = 0.0f;
    if (bi != bj) {
        #pragma unroll
        for (int im = 0; im < 4; ++im) {
            #pragma unroll
            for (int r = 0; r < 4; ++r) {
                uint2 ma = mAs[wm + im * 16 + fquad * 4 + r];
                #pragma unroll
                for (int in = 0; in < 4; ++in) {
                    float d = fmaf(-2.0f, acc[im][in][r],
                                   __uint_as_float(ma.x) + __uint_as_float(mb[in].x));
                    lsum += (ma.y == mb[in].y) ? d : fmaxf(MARGIN - d, 0.0f);
                }
            }
        }
        lsum *= 2.0f;   // (i,j) and (j,i)
    } else {
        #pragma unroll
        for (int im = 0; im < 4; ++im) {
            #pragma unroll
            for (int r = 0; r < 4; ++r) {
                int rl = wm + im * 16 + fquad * 4 + r;
                uint2 ma = mAs[rl];
                #pragma unroll
                for (int in = 0; in < 4; ++in) {
                    int cl = wn + in * 16 + frow;
                    float d = fmaf(-2.0f, acc[im][in][r],
                                   __uint_as_float(ma.x) + __uint_as_float(mb[in].x));
                    float c = (ma.y == mb[in].y) ? d : fmaxf(MARGIN - d, 0.0f);
                    float w = (rl < cl) ? 2.0f : ((rl == cl) ? 1.0f : 0.0f);
                    lsum += w * c;
                }
            }
        }
    }
    return lsum;
}

#define WAITV(n) asm volatile("s_waitcnt vmcnt(" #n ")" ::: "memory")
#define SBAR()   do { __builtin_amdgcn_sched_barrier(0);                 \
                      __builtin_amdgcn_s_barrier();                      \
                      __builtin_amdgcn_sched_barrier(0); } while (0)

// ---------------------------------------------------------------------------
// Main: 1040 blocks, each computes TWO consecutive triangular 128x128 Gram
// tiles with the r6 counted-vmcnt rotating pipeline (34 KB LDS -> 4
// blocks/CU). Pair 1's staging (meta + units 0,1) is issued BEFORE pair 0's
// epilogue so its L2 latency hides under the epilogue VALU work — per-block
// fixed latency amortized 2x. One partial per block.
// ---------------------------------------------------------------------------
__global__ __launch_bounds__(256, 4) void loss_kernel(
        const uint8_t* __restrict__ Xq, const uint2* __restrict__ metaG,
        float* __restrict__ partials) {
    __shared__ __align__(16) uint8_t As[2][8192];   // 16 KB (K=64 units)
    __shared__ __align__(16) uint8_t Bs[2][8192];   // 16 KB
    __shared__ __align__(16) uint2   mA[2][BM], mB[2][BM];  // per-pair meta
    __shared__ float wsum[4];

    const int tid  = threadIdx.x;
    const int wave = tid >> 6;
    const int lane = tid & 63;

    const int frow  = lane & 15;
    const int fquad = lane >> 4;
    const int wm4 = (wave >> 1) * 4;
    const int wn4 = (wave & 1) * 4;
    const int wm  = wm4 * 16, wn = wn4 * 16;
    const int fragOff = fquad * 256 + frow * 16;
    const size_t srcLane = (size_t)(lane & 15) * 64 + (size_t)(lane >> 4) * 16;

    // ---- decode both pairs: p -> (bi, bj), bi <= bj ----
    int bis[2], bjs[2];
    #pragma unroll
    for (int s = 0; s < 2; ++s) {
        const int p = 2 * blockIdx.x + s;
        float tf = 2.0f * TILES + 1.0f;
        int bi = (int)((tf - sqrtf(tf * tf - 8.0f * (float)p)) * 0.5f);
        if (bi < 0) bi = 0;
        while (bi > 0 && (bi * TILES - bi * (bi - 1) / 2) > p) --bi;
        while (((bi + 1) * TILES - (bi + 1) * bi / 2) <= p) ++bi;
        bis[s] = bi;
        bjs[s] = bi + (p - (bi * TILES - bi * (bi - 1) / 2));
    }

    const uint8_t* gA0 = Xq + (size_t)bis[0] * BM * 64 + srcLane;
    const uint8_t* gB0 = Xq + (size_t)bjs[0] * BM * 64 + srcLane;
    const uint8_t* gA1 = Xq + (size_t)bis[1] * BM * 64 + srcLane;
    const uint8_t* gB1 = Xq + (size_t)bjs[1] * BM * 64 + srcLane;

    f32x4 acc[4][4];
    #pragma unroll
    for (int im = 0; im < 4; ++im)
        #pragma unroll
        for (int in = 0; in < 4; ++in)
            acc[im][in] = (f32x4){0.f, 0.f, 0.f, 0.f};

    // ---- pair 0: issue meta(2) + u0(4) + u1(4) = 10 in flight ----
    async_copy16((const uint8_t*)(metaG + bis[0] * BM) + (size_t)lane * 16, mA[0]);
    async_copy16((const uint8_t*)(metaG + bjs[0] * BM) + (size_t)lane * 16, mB[0]);
    stage_unit(gA0,           gB0,           As[0], Bs[0], wave);
    stage_unit(gA0 + PLANE_Q, gB0 + PLANE_Q, As[1], Bs[1], wave);

    WAITV(4); SBAR();                       // meta+u0 ready; u1 in flight
    compute_unit(As[0], Bs[0], wm4, wn4, fragOff, acc);
    SBAR();                                 // u0 reads retired everywhere
    stage_unit(gA0 + 2 * PLANE_Q, gB0 + 2 * PLANE_Q, As[0], Bs[0], wave);

    WAITV(4); SBAR();                       // u1 ready; u2 in flight
    compute_unit(As[1], Bs[1], wm4, wn4, fragOff, acc);
    SBAR();                                 // u1 reads retired
    stage_unit(gA0 + 3 * PLANE_Q, gB0 + 3 * PLANE_Q, As[1], Bs[1], wave);

    WAITV(4); SBAR();                       // u2 ready; u3 in flight
    compute_unit(As[0], Bs[0], wm4, wn4, fragOff, acc);

    WAITV(0); SBAR();                       // u3 ready
    compute_unit(As[1], Bs[1], wm4, wn4, fragOff, acc);
    SBAR();                                 // u3 reads retired -> LDS reusable

    // ---- issue pair 1 staging NOW; hide its latency under pair-0 epilogue
    async_copy16((const uint8_t*)(metaG + bis[1] * BM) + (size_t)lane * 16, mA[1]);
    async_copy16((const uint8_t*)(metaG + bjs[1] * BM) + (size_t)lane * 16, mB[1]);
    stage_unit(gA1,           gB1,           As[0], Bs[0], wave);
    stage_unit(gA1 + PLANE_Q, gB1 + PLANE_Q, As[1], Bs[1], wave);

    float lsum = epilogue(acc, mA[0], mB[0], bis[0], bjs[0],
                          wm, wn, frow, fquad);

    #pragma unroll
    for (int im = 0; im < 4; ++im)
        #pragma unroll
        for (int in = 0; in < 4; ++in)
            acc[im][in] = (f32x4){0.f, 0.f, 0.f, 0.f};

    // ---- pair 1 pipeline (same ledger) ----
    WAITV(4); SBAR();
    compute_unit(As[0], Bs[0], wm4, wn4, fragOff, acc);
    SBAR();
    stage_unit(gA1 + 2 * PLANE_Q, gB1 + 2 * PLANE_Q, As[0], Bs[0], wave);

    WAITV(4); SBAR();
    compute_unit(As[1], Bs[1], wm4, wn4, fragOff, acc);
    SBAR();
    stage_unit(gA1 + 3 * PLANE_Q, gB1 + 3 * PLANE_Q, As[1], Bs[1], wave);

    WAITV(4); SBAR();
    compute_unit(As[0], Bs[0], wm4, wn4, fragOff, acc);

    WAITV(0); SBAR();
    compute_unit(As[1], Bs[1], wm4, wn4, fragOff, acc);

    lsum += epilogue(acc, mA[1], mB[1], bis[1], bjs[1],
                     wm, wn, frow, fquad);

    // ---- block reduction -> one partial ----
    #pragma unroll
    for (int o = 32; o > 0; o >>= 1) lsum += __shfl_down(lsum, o, 64);
    if (lane == 0) wsum[wave] = lsum;
    __syncthreads();
    if (tid == 0) partials[blockIdx.x] = wsum[0] + wsum[1] + wsum[2] + wsum[3];
}

// ---------------------------------------------------------------------------
// Final deterministic reduce of NBLK partials -> scaled scalar.
// ---------------------------------------------------------------------------
__global__ __launch_bounds__(256) void reduce_kernel(
        const float* __restrict__ partials, float* __restrict__ out,
        int n, float scale) {
    float s = 0.0f;
    for (int i = threadIdx.x; i < n; i += 256) s += partials[i];
    __shared__ float w[4];
    #pragma unroll
    for (int o = 32; o > 0; o >>= 1) s += __shfl_down(s, o, 64);
    int wave = threadIdx.x >> 6, lane = threadIdx.x & 63;
    if (lane == 0) w[wave] = s;
    __syncthreads();
    if (threadIdx.x == 0) out[0] = (w[0] + w[1] + w[2] + w[3]) * scale;
}

extern "C" void kernel_launch(void* const* d_in, const int* in_sizes, int n_in,
                              void* d_out, int out_size, void* d_ws, size_t ws_size,
                              hipStream_t stream) {
    (void)in_sizes; (void)n_in; (void)out_size; (void)ws_size;
    const float* X   = (const float*)d_in[0];
    const int*   tgt = (const int*)d_in[1];

    uint8_t* Xq       = (uint8_t*)d_ws;                              // 2 MB (4 planes)
    uint2*   metaG    = (uint2*)((char*)d_ws + 4 * PLANE_Q);         // 64 KB
    float*   partials = (float*)((char*)metaG + (size_t)N * 8);      // NBLK

    prep_kernel<<<N / 4, 256, 0, stream>>>(X, tgt, Xq, metaG);
    loss_kernel<<<NBLK, 256, 0, stream>>>(Xq, metaG, partials);

    const float scale = (float)(1.0 / ((double)N * ((double)N - 1.0) * 2.0));
    reduce_kernel<<<1, 256, 0, stream>>>(partials, (float*)d_out, NBLK, scale);
}